// Round 11
// baseline (605.130 us; speedup 1.0000x reference)
//
#include <hip/hip_runtime.h>
#include <math.h>

// N=50000, E=800000, IN=128, H=4, C=64, HC=256
#define HEADS 4
#define CH 64
#define HC 256

typedef short bf16x8 __attribute__((ext_vector_type(8)));
typedef float f32x4 __attribute__((ext_vector_type(4)));
typedef float f32x2 __attribute__((ext_vector_type(2)));
typedef unsigned int u32x4 __attribute__((ext_vector_type(4)));

__device__ __forceinline__ float bf2f(unsigned short u) {
  unsigned int v = ((unsigned int)u) << 16;
  return __builtin_bit_cast(float, v);
}
__device__ __forceinline__ unsigned short f2bf(float f) {
  unsigned int u = __builtin_bit_cast(unsigned int, f);
  unsigned int r = u + 0x7fffu + ((u >> 16) & 1u);
  return (unsigned short)(r >> 16);
}
// leaky_relu(x, 0.2) == max(x, 0.2x)
__device__ __forceinline__ float leaky02(float x) { return fmaxf(x, 0.2f * x); }
// bf16 pair (packed in a u32) -> two floats (lo, hi)
__device__ __forceinline__ f32x2 bfpair(unsigned int w) {
  f32x2 r;
  r.x = __builtin_bit_cast(float, w << 16);
  r.y = __builtin_bit_cast(float, w & 0xffff0000u);
  return r;
}
// packed f32 fma: acc += e2 * h2 (exact f32 FMA semantics, 1 instr for 2 lanes)
__device__ __forceinline__ void pkfma(f32x2& acc, f32x2 e2, f32x2 h2) {
  asm("v_pk_fma_f32 %0, %1, %2, %0" : "+v"(acc) : "v"(e2), "v"(h2));
}
// select float4 component by runtime index 0..3 (2-level cndmask, no scratch)
__device__ __forceinline__ float sel4(float4 v, int i) {
  float lo = (i & 1) ? v.y : v.x;
  float hi = (i & 1) ? v.w : v.z;
  return (i & 2) ? hi : lo;
}

// Async global->LDS, 16B per lane. LDS dest is wave-uniform base + lane*16.
__device__ __forceinline__ void gload_lds16(const unsigned short* g, unsigned short* l) {
  __builtin_amdgcn_global_load_lds(
      (const __attribute__((address_space(1))) unsigned int*)g,
      (__attribute__((address_space(3))) unsigned int*)l, 16, 0, 0);
}

// ---------------------------------------------------------------------------
// Fused prep kernel: convert x fp32->bf16 (blocks [0,t4b)) + the 3 weight
// transposes Bt[512][K] = [W|SW]^T (blocks after) + dummy-row init
// (hb[Nn]=0, s[Nn]=-1e30) for maskless CSR padding.
// ---------------------------------------------------------------------------
__device__ __forceinline__ void transpose_body(
    const float* __restrict__ W, const float* __restrict__ SW,
    unsigned short* __restrict__ Bt, int K, int kx, int cy,
    unsigned short (*tile)[72], int t) {
  int k0 = kx * 64;
  int c0 = cy * 64;
  const float* __restrict__ src = (c0 < 256) ? W : SW;
  int cc = (c0 < 256) ? c0 : c0 - 256;
  int r = t >> 2, q4 = (t & 3) * 16;
#pragma unroll
  for (int q = 0; q < 4; q++) {
    float4 v = *reinterpret_cast<const float4*>(src + (size_t)(k0 + r) * 256 + cc + q4 + q * 4);
    tile[q4 + q * 4 + 0][r] = f2bf(v.x);
    tile[q4 + q * 4 + 1][r] = f2bf(v.y);
    tile[q4 + q * 4 + 2][r] = f2bf(v.z);
    tile[q4 + q * 4 + 3][r] = f2bf(v.w);
  }
  __syncthreads();
  int c = t >> 2, kq = (t & 3) * 16;
#pragma unroll
  for (int q = 0; q < 2; q++) {
    bf16x8 v = *reinterpret_cast<const bf16x8*>(&tile[c][kq + q * 8]);
    *reinterpret_cast<bf16x8*>(Bt + (size_t)(c0 + c) * K + k0 + kq + q * 8) = v;
  }
}

__global__ __launch_bounds__(256) void prep_kernel(
    const float* __restrict__ x, unsigned short* __restrict__ xb, int total4, int t4b,
    const float* __restrict__ W0, const float* __restrict__ SW0, unsigned short* __restrict__ Bt0,
    const float* __restrict__ W1, const float* __restrict__ SW1, unsigned short* __restrict__ Bt1,
    const float* __restrict__ W2, const float* __restrict__ SW2, unsigned short* __restrict__ Bt2,
    unsigned short* __restrict__ hb_dummy, float* __restrict__ s_dummy) {
  __shared__ unsigned short tile[64][72];
  int b = blockIdx.x;
  int t = threadIdx.x;
  if (b < t4b) {
    if (b == 0) {  // dummy-row init (512B hb row + 4 floats of s)
      if (t < 64) reinterpret_cast<ushort4*>(hb_dummy)[t] = (ushort4){0, 0, 0, 0};
      if (t < 4) s_dummy[t] = -1e30f;
    }
    int i = b * 256 + t;
    if (i >= total4) return;
    float4 v = reinterpret_cast<const float4*>(x)[i];
    ushort4 o;
    o.x = f2bf(v.x); o.y = f2bf(v.y); o.z = f2bf(v.z); o.w = f2bf(v.w);
    reinterpret_cast<ushort4*>(xb)[i] = o;
  } else if (b < t4b + 16) {
    int local = b - t4b;
    transpose_body(W0, SW0, Bt0, 128, local & 1, local >> 1, tile, t);
  } else if (b < t4b + 48) {
    int local = b - t4b - 16;
    transpose_body(W1, SW1, Bt1, 256, local & 3, local >> 2, tile, t);
  } else {
    int local = b - t4b - 48;
    transpose_body(W2, SW2, Bt2, 256, local & 3, local >> 2, tile, t);
  }
}

// ---------------------------------------------------------------------------
// bf16 MFMA GEMM (persistent weight-stationary, no atomics) — unchanged R9/R10.
// ---------------------------------------------------------------------------
template <int K>
__global__ __launch_bounds__(256, 2) void gemm_mfma(
    const unsigned short* __restrict__ xb, const unsigned short* __restrict__ Bt,
    const float* __restrict__ Sb, const float* __restrict__ a_src,
    const float* __restrict__ a_dst, unsigned short* __restrict__ h,
    unsigned short* __restrict__ skipb, float* __restrict__ s,
    float* __restrict__ d, int M, int npanels) {
  extern __shared__ unsigned short Bs[];  // [128][K] bf16, XOR-swizzled rows

  const int t = threadIdx.x;
  const int cg = blockIdx.x >> 7;   // 0..3
  const int rg = blockIdx.x & 127;  // 0..127
  const int colBase = cg * 128;

  const int w = t >> 6, lane = t & 63;
  const int wr = (w >> 1) * 64, wc = (w & 1) * 64;
  const int lrow = lane & 15, lq = lane >> 4;
  constexpr int nt = K >> 5;

  // ---- B fill: LDS linear dest, inverse-swizzled global source (rule 21).
  {
    constexpr int rowchunks = K >> 3;  // 16B chunks per row
#pragma unroll
    for (int it = 0; it < (K >> 4); ++it) {
      int c = t + (it << 8);
      int lc = c / rowchunks;
      int ci = c - lc * rowchunks;
      unsigned int src_in_row = ((unsigned int)(ci << 4)) ^ (unsigned int)((lc & 7) << 4);
      gload_lds16(Bt + (size_t)(colBase + lc) * K + (src_in_row >> 1), Bs + (size_t)c * 8);
    }
  }

  // Per-wave B read bases (byte offsets) + swizzle keys.
  unsigned int bRow[4], bSwz[4];
#pragma unroll
  for (int j = 0; j < 4; j++) {
    int lc = wc + j * 16 + lrow;
    bRow[j] = (unsigned int)lc * (K * 2);
    bSwz[j] = (unsigned int)((lc & 7) << 4);
  }

  // Epilogue constants (h path).
  const int head = (colBase + wc) >> 6;  // valid for cg<2
  float as_w[4], ad_w[4];
  if (cg < 2) {
#pragma unroll
    for (int j = 0; j < 4; j++) {
      as_w[j] = a_src[head * 64 + j * 16 + lrow];
      ad_w[j] = a_dst[head * 64 + j * 16 + lrow];
    }
  }

  __syncthreads();  // B ready; only barrier in the kernel

  for (int p = rg; p < npanels; p += 128) {
    const int rowBase = p * 128;

    const unsigned short* apan[4];
#pragma unroll
    for (int i = 0; i < 4; i++) {
      int gr = rowBase + wr + i * 16 + lrow;
      if (gr >= M) gr = M - 1;
      apan[i] = xb + (size_t)gr * K + lq * 8;
    }

    f32x4 acc[4][4];
#pragma unroll
    for (int i = 0; i < 4; i++)
#pragma unroll
      for (int j = 0; j < 4; j++) acc[i][j] = (f32x4){0.f, 0.f, 0.f, 0.f};

    bf16x8 af[2][4];
#pragma unroll
    for (int i = 0; i < 4; i++) af[0][i] = *reinterpret_cast<const bf16x8*>(apan[i]);

#pragma unroll
    for (int st = 0; st < nt; ++st) {
      const int cur = st & 1, nxt = cur ^ 1;
      if (st + 1 < nt) {
#pragma unroll
        for (int i = 0; i < 4; i++)
          af[nxt][i] = *reinterpret_cast<const bf16x8*>(apan[i] + (st + 1) * 32);
      }
      bf16x8 bfr[4];
      const unsigned int kb = (unsigned int)(st * 64) + (unsigned int)(lq << 4);
#pragma unroll
      for (int j = 0; j < 4; j++)
        bfr[j] = *reinterpret_cast<const bf16x8*>((const char*)Bs + bRow[j] + (kb ^ bSwz[j]));
#pragma unroll
      for (int i = 0; i < 4; i++)
#pragma unroll
        for (int j = 0; j < 4; j++)
          acc[i][j] = __builtin_amdgcn_mfma_f32_16x16x32_bf16(af[cur][i], bfr[j], acc[i][j], 0, 0, 0);
    }

    // ---- Panel epilogue. C/D layout: col=lane&15, row=(lane>>4)*4+reg
    if (cg < 2) {
#pragma unroll
      for (int i = 0; i < 4; i++) {
#pragma unroll
        for (int j = 0; j < 4; j++) {
          int gcol = colBase + wc + j * 16 + lrow;
#pragma unroll
          for (int r2 = 0; r2 < 4; r2++) {
            int grow = rowBase + wr + i * 16 + lq * 4 + r2;
            if (grow < M) h[(size_t)grow * 256 + gcol] = f2bf(acc[i][j][r2]);
          }
        }
      }
      // fused s/d (no max, no atomic)
#pragma unroll
      for (int i = 0; i < 4; i++) {
#pragma unroll
        for (int r2 = 0; r2 < 4; r2++) {
          float ps = acc[i][0][r2] * as_w[0] + acc[i][1][r2] * as_w[1] +
                     acc[i][2][r2] * as_w[2] + acc[i][3][r2] * as_w[3];
          float pd = acc[i][0][r2] * ad_w[0] + acc[i][1][r2] * ad_w[1] +
                     acc[i][2][r2] * ad_w[2] + acc[i][3][r2] * ad_w[3];
#pragma unroll
          for (int off = 1; off < 16; off <<= 1) {  // reduce across lrow (same lq)
            ps += __shfl_xor(ps, off, 64);
            pd += __shfl_xor(pd, off, 64);
          }
          int grow = rowBase + wr + i * 16 + lq * 4 + r2;
          if (grow < M && lrow == 0) { s[grow * 4 + head] = ps; d[grow * 4 + head] = pd; }
        }
      }
    } else {
#pragma unroll
      for (int i = 0; i < 4; i++) {
#pragma unroll
        for (int j = 0; j < 4; j++) {
          int c = colBase - 256 + wc + j * 16 + lrow;
          float sbv = Sb[c];
#pragma unroll
          for (int r2 = 0; r2 < 4; r2++) {
            int grow = rowBase + wr + i * 16 + lq * 4 + r2;
            if (grow < M) skipb[(size_t)grow * 256 + c] = f2bf(acc[i][j][r2] + sbv);
          }
        }
      }
    }
  }
}

// ---------------------------------------------------------------------------
// CSR build. Padding (to multiple of 16 now) holds the DUMMY index Nn
// (written by offsets_kernel); s[Nn]=-1e30 -> ev==0, hb[Nn]=0.
// ---------------------------------------------------------------------------
__global__ void hist_kernel(const int* __restrict__ ei, int* __restrict__ counts, int E) {
  int e = blockIdx.x * 256 + threadIdx.x;
  if (e < E) atomicAdd(&counts[ei[E + e]], 1);
}

__global__ __launch_bounds__(256) void offsets_kernel(
    const int* __restrict__ counts, int* __restrict__ offsets,
    int* __restrict__ cursor, int* __restrict__ total,
    int* __restrict__ csr, int Nn) {
  int n = blockIdx.x * 256 + threadIdx.x;
  int lane = threadIdx.x & 63;
  int c = (n < Nn) ? counts[n] : 0;
  int pc = (c + 15) & ~15;
  int incl = pc;
#pragma unroll
  for (int off = 1; off < 64; off <<= 1) {
    int tv = __shfl_up(incl, off, 64);
    if (lane >= off) incl += tv;
  }
  int wavesum = __shfl(incl, 63, 64);
  int base = 0;
  if (lane == 63) base = atomicAdd(total, wavesum);
  base = __shfl(base, 63, 64);
  if (n < Nn) {
    int pos = base + incl - pc;
    offsets[n] = pos;
    cursor[n] = pos;
    for (int q = pos + c; q < pos + pc; ++q) csr[q] = Nn;  // dummy padding
  }
}

__global__ void scatter_kernel(const int* __restrict__ ei, int* __restrict__ cursor,
                               int* __restrict__ csr, int E) {
  int e = blockIdx.x * 256 + threadIdx.x;
  if (e < E) {
    int dn = ei[E + e];
    int pos = atomicAdd(&cursor[dn], 1);
    csr[pos] = ei[e];
  }
}

// ---------------------------------------------------------------------------
// Aggregation v5: one wave per node, 16 edges per iteration.
//  P1: 16 edges x 4 heads = 64 combos = 64 lanes -> each lane computes ONE
//      ev (edge=lane&15, head=lane>>4) into evs[lane]. Zero redundancy.
//  P2: halves take 8 edges each (sub*8..+7): evs via 2x f32x4 broadcast
//      ds_read, hb rows via 8 independent b128 gathers (2x the in-flight
//      loads of v4 -> latency hiding for the memory-bound gather), pkfma.
// Maskless: CSR pad-16 points at dummy node Nn (ev=0, hb row=0).
// Softmax shift m = self-loop logit (no global max, no atomics).
// ---------------------------------------------------------------------------
__global__ __launch_bounds__(256) void agg_kernel(
    const unsigned short* __restrict__ hb, const float* __restrict__ s,
    const float* __restrict__ d,
    const int* __restrict__ offsets, const int* __restrict__ counts,
    const int* __restrict__ csr,
    const float* __restrict__ b, const unsigned short* __restrict__ skipb,
    float* __restrict__ xout_f, unsigned short* __restrict__ xout_b,
    int Nn, int write_f) {
  __shared__ float evs_all[4][64];
  int wid = threadIdx.x >> 6;
  int n = blockIdx.x * 4 + wid;
  if (n >= Nn) return;
  int lane = threadIdx.x & 63;
  int sub = lane >> 5;
  int li = lane & 31;
  int head = li >> 3;     // own head (P2/epilogue)
  int col = li * 8;
  float* evs = evs_all[wid];

  int beg = offsets[n];
  int cnt = counts[n];
  int pend = beg + ((cnt + 15) & ~15);

  // Per-head s/d of node n (one vector load each, select by head).
  float4 sn4 = *reinterpret_cast<const float4*>(s + n * 4);
  float4 dn4 = *reinterpret_cast<const float4*>(d + n * 4);
  float dv = sel4(dn4, head);
  float m = leaky02(sel4(sn4, head) + dv);   // self-loop logit, own head
  const int hp = lane >> 4;                  // P1 head
  const int e16 = lane & 15;                 // P1 edge
  float dvp = sel4(dn4, hp);
  float mp = leaky02(sel4(sn4, hp) + dvp);

  f32x2 a2[4];
#pragma unroll
  for (int k2 = 0; k2 < 4; k2++) a2[k2] = (f32x2){0.f, 0.f};
  float dsum = 0.f;

  for (int i0 = beg; i0 < pend; i0 += 16) {
    // --- P1: one (edge,head) ev per lane ---
    int snp = csr[i0 + e16];
    float ev = __expf(leaky02(s[snp * 4 + hp] + dvp) - mp);
    evs[lane] = ev;  // layout: evs[hp*16 + e16]

    // --- P2: this half's 8 edges ---
    int4 sa = *reinterpret_cast<const int4*>(csr + i0 + sub * 8);
    int4 sb2 = *reinterpret_cast<const int4*>(csr + i0 + sub * 8 + 4);
    u32x4 w0 = __builtin_bit_cast(u32x4, *reinterpret_cast<const bf16x8*>(hb + (size_t)sa.x * HC + col));
    u32x4 w1 = __builtin_bit_cast(u32x4, *reinterpret_cast<const bf16x8*>(hb + (size_t)sa.y * HC + col));
    u32x4 w2 = __builtin_bit_cast(u32x4, *reinterpret_cast<const bf16x8*>(hb + (size_t)sa.z * HC + col));
    u32x4 w3 = __builtin_bit_cast(u32x4, *reinterpret_cast<const bf16x8*>(hb + (size_t)sa.w * HC + col));
    u32x4 w4 = __builtin_bit_cast(u32x4, *reinterpret_cast<const bf16x8*>(hb + (size_t)sb2.x * HC + col));
    u32x4 w5 = __builtin_bit_cast(u32x4, *reinterpret_cast<const bf16x8*>(hb + (size_t)sb2.y * HC + col));
    u32x4 w6 = __builtin_bit_cast(u32x4, *reinterpret_cast<const bf16x8*>(hb + (size_t)sb2.z * HC + col));
    u32x4 w7 = __builtin_bit_cast(u32x4, *reinterpret_cast<const bf16x8*>(hb + (size_t)sb2.w * HC + col));

    f32x4 eva = *reinterpret_cast<const f32x4*>(&evs[head * 16 + sub * 8]);
    f32x4 evb = *reinterpret_cast<const f32x4*>(&evs[head * 16 + sub * 8 + 4]);
    dsum += eva[0] + eva[1] + eva[2] + eva[3] + evb[0] + evb[1] + evb[2] + evb[3];

    f32x2 e0 = (f32x2){eva[0], eva[0]}, e1 = (f32x2){eva[1], eva[1]};
    f32x2 e2 = (f32x2){eva[2], eva[2]}, e3 = (f32x2){eva[3], eva[3]};
    f32x2 e4 = (f32x2){evb[0], evb[0]}, e5 = (f32x2){evb[1], evb[1]};
    f32x2 e6 = (f32x2){evb[2], evb[2]}, e7 = (f32x2){evb[3], evb[3]};
#pragma unroll
    for (int k2 = 0; k2 < 4; k2++) {
      pkfma(a2[k2], e0, bfpair(w0[k2]));
      pkfma(a2[k2], e1, bfpair(w1[k2]));
      pkfma(a2[k2], e2, bfpair(w2[k2]));
      pkfma(a2[k2], e3, bfpair(w3[k2]));
      pkfma(a2[k2], e4, bfpair(w4[k2]));
      pkfma(a2[k2], e5, bfpair(w5[k2]));
      pkfma(a2[k2], e6, bfpair(w6[k2]));
      pkfma(a2[k2], e7, bfpair(w7[k2]));
    }
  }

#pragma unroll
  for (int k2 = 0; k2 < 4; k2++) {
    a2[k2].x += __shfl_xor(a2[k2].x, 32, 64);
    a2[k2].y += __shfl_xor(a2[k2].y, 32, 64);
  }
  dsum += __shfl_xor(dsum, 32, 64);

  // self loop: exp(m - m) == 1
  bf16x8 hs = *reinterpret_cast<const bf16x8*>(hb + (size_t)n * HC + col);
  float a[8];
#pragma unroll
  for (int k2 = 0; k2 < 4; k2++) { a[2 * k2] = a2[k2].x; a[2 * k2 + 1] = a2[k2].y; }
#pragma unroll
  for (int k = 0; k < 8; k++) a[k] += bf2f((unsigned short)hs[k]);
  dsum += 1.f;

  if (sub == 0) {
    float inv = 1.f / (dsum + 1e-16f);
    bf16x8 sk = *reinterpret_cast<const bf16x8*>(skipb + (size_t)n * HC + col);
    float4 b0 = *reinterpret_cast<const float4*>(b + col);
    float4 b1 = *reinterpret_cast<const float4*>(b + col + 4);
    float bv[8] = {b0.x, b0.y, b0.z, b0.w, b1.x, b1.y, b1.z, b1.w};
    float res[8];
#pragma unroll
    for (int k = 0; k < 8; k++) {
      float v = a[k] * inv + bv[k] + bf2f((unsigned short)sk[k]);
      res[k] = v > 0.f ? v : expm1f(v);
    }
    if (write_f) {
      float4 r0 = make_float4(res[0], res[1], res[2], res[3]);
      float4 r1 = make_float4(res[4], res[5], res[6], res[7]);
      *reinterpret_cast<float4*>(xout_f + (size_t)n * HC + col) = r0;
      *reinterpret_cast<float4*>(xout_f + (size_t)n * HC + col + 4) = r1;
    } else {
      bf16x8 o;
#pragma unroll
      for (int k = 0; k < 8; k++) o[k] = (short)f2bf(res[k]);
      *reinterpret_cast<bf16x8*>(xout_b + (size_t)n * HC + col) = o;
    }
  }
}

// ---------------------------------------------------------------------------
extern "C" void kernel_launch(void* const* d_in, const int* in_sizes, int n_in,
                              void* d_out, int out_size, void* d_ws, size_t ws_size,
                              hipStream_t stream) {
  const float* x = (const float*)d_in[0];
  const int* ei = (const int*)d_in[1];
  const int Nn = in_sizes[0] / 128;  // 50000
  const int E = in_sizes[1] / 2;     // 800000
  const int EPS = E + 15 * Nn;       // max padded CSR size (pad-16)

  const float* W[3]; const float* asrc[3]; const float* adst[3];
  const float* bb[3]; const float* SW[3]; const float* Sb[3];
  for (int l = 0; l < 3; l++) {
    W[l]    = (const float*)d_in[2 + 6 * l + 0];
    asrc[l] = (const float*)d_in[2 + 6 * l + 1];
    adst[l] = (const float*)d_in[2 + 6 * l + 2];
    bb[l]   = (const float*)d_in[2 + 6 * l + 3];
    SW[l]   = (const float*)d_in[2 + 6 * l + 4];
    Sb[l]   = (const float*)d_in[2 + 6 * l + 5];
  }

  // Workspace layout. hb gets +1 dummy row (index Nn); sbuf +4 dummy floats.
  char* p = (char*)d_ws;
  unsigned short* hb    = (unsigned short*)p; p += (size_t)(Nn + 1) * HC * 2;
  unsigned short* xb    = (unsigned short*)p; p += (size_t)Nn * HC * 2;
  unsigned short* x1b   = (unsigned short*)p; p += (size_t)Nn * 128 * 2;
  unsigned short* Bt0   = (unsigned short*)p; p += (size_t)512 * 128 * 2;
  unsigned short* Bt1   = (unsigned short*)p; p += (size_t)512 * 256 * 2;
  unsigned short* Bt2   = (unsigned short*)p; p += (size_t)512 * 256 * 2;
  unsigned short* skipb = (unsigned short*)p; p += (size_t)Nn * HC * 2;
  float* sbuf  = (float*)p; p += (size_t)Nn * HEADS * 4 + 16;
  float* dbuf  = (float*)p; p += (size_t)Nn * HEADS * 4;
  char* zero_base = p;
  int* counts  = (int*)p; p += (size_t)Nn * 4;
  int* total   = (int*)p; p += 16;
  size_t zero_bytes = (size_t)((char*)p - zero_base);
  int* offsets = (int*)p; p += ((size_t)Nn * 4 + 15) & ~(size_t)15;
  int* cursor  = (int*)p; p += ((size_t)Nn * 4 + 15) & ~(size_t)15;
  int* csr     = (int*)p; p += (size_t)EPS * 4;

  // --- Tiny memset: counts + total only (csr padding written by offsets) ---
  hipMemsetAsync(zero_base, 0, zero_bytes, stream);

  // --- Fused prep: convert x + 3 weight transposes + dummy-row init ---
  int t4 = Nn * 128 / 4;
  int t4b = (t4 + 255) / 256;
  prep_kernel<<<t4b + 80, 256, 0, stream>>>(x, x1b, t4, t4b,
                                            W[0], SW[0], Bt0,
                                            W[1], SW[1], Bt1,
                                            W[2], SW[2], Bt2,
                                            hb + (size_t)Nn * HC, sbuf + (size_t)Nn * 4);

  // --- CSR build (once; dst is layer-invariant) ---
  hist_kernel<<<(E + 255) / 256, 256, 0, stream>>>(ei, counts, E);
  offsets_kernel<<<(Nn + 255) / 256, 256, 0, stream>>>(counts, offsets, cursor, total, csr, Nn);
  scatter_kernel<<<(E + 255) / 256, 256, 0, stream>>>(ei, cursor, csr, E);

  // --- Layers ---
  const unsigned short* BtL[3] = {Bt0, Bt1, Bt2};
  int npanels = (Nn + 127) / 128;  // 391
  int nblk4 = (Nn + 3) / 4;
  for (int l = 0; l < 3; l++) {
    const unsigned short* xin = (l == 0) ? x1b : xb;
    if (l == 0) {
      gemm_mfma<128><<<512, 256, 128 * 128 * 2, stream>>>(
          xin, BtL[l], Sb[l], asrc[l], adst[l], hb, skipb, sbuf, dbuf, Nn, npanels);
    } else {
      gemm_mfma<256><<<512, 256, 128 * 256 * 2, stream>>>(
          xin, BtL[l], Sb[l], asrc[l], adst[l], hb, skipb, sbuf, dbuf, Nn, npanels);
    }
    agg_kernel<<<nblk4, 256, 0, stream>>>(hb, sbuf, dbuf, offsets, counts, csr,
                                          bb[l], skipb, (float*)d_out, xb,
                                          Nn, (l == 2) ? 1 : 0);
  }
}

// Round 12
// 558.322 us; speedup vs baseline: 1.0838x; 1.0838x over previous
//
#include <hip/hip_runtime.h>
#include <math.h>

// N=50000, E=800000, IN=128, H=4, C=64, HC=256
#define HEADS 4
#define CH 64
#define HC 256

typedef short bf16x8 __attribute__((ext_vector_type(8)));
typedef float f32x4 __attribute__((ext_vector_type(4)));
typedef float f32x2 __attribute__((ext_vector_type(2)));
typedef unsigned int u32x4 __attribute__((ext_vector_type(4)));

__device__ __forceinline__ float bf2f(unsigned short u) {
  unsigned int v = ((unsigned int)u) << 16;
  return __builtin_bit_cast(float, v);
}
__device__ __forceinline__ unsigned short f2bf(float f) {
  unsigned int u = __builtin_bit_cast(unsigned int, f);
  unsigned int r = u + 0x7fffu + ((u >> 16) & 1u);
  return (unsigned short)(r >> 16);
}
// leaky_relu(x, 0.2) == max(x, 0.2x)
__device__ __forceinline__ float leaky02(float x) { return fmaxf(x, 0.2f * x); }
// bf16 pair (packed in a u32) -> two floats (lo, hi)
__device__ __forceinline__ f32x2 bfpair(unsigned int w) {
  f32x2 r;
  r.x = __builtin_bit_cast(float, w << 16);
  r.y = __builtin_bit_cast(float, w & 0xffff0000u);
  return r;
}
// packed f32 fma: acc += e2 * h2 (exact f32 FMA semantics, 1 instr for 2 lanes)
__device__ __forceinline__ void pkfma(f32x2& acc, f32x2 e2, f32x2 h2) {
  asm("v_pk_fma_f32 %0, %1, %2, %0" : "+v"(acc) : "v"(e2), "v"(h2));
}

// Async global->LDS, 16B per lane. LDS dest is wave-uniform base + lane*16.
__device__ __forceinline__ void gload_lds16(const unsigned short* g, unsigned short* l) {
  __builtin_amdgcn_global_load_lds(
      (const __attribute__((address_space(1))) unsigned int*)g,
      (__attribute__((address_space(3))) unsigned int*)l, 16, 0, 0);
}

// ---------------------------------------------------------------------------
// Fused prep kernel: convert x fp32->bf16 (blocks [0,t4b)) + the 3 weight
// transposes Bt[512][K] = [W|SW]^T (blocks after) + dummy-row init
// (hb[Nn]=0, s[Nn]=-1e30) for maskless CSR padding.
// ---------------------------------------------------------------------------
__device__ __forceinline__ void transpose_body(
    const float* __restrict__ W, const float* __restrict__ SW,
    unsigned short* __restrict__ Bt, int K, int kx, int cy,
    unsigned short (*tile)[72], int t) {
  int k0 = kx * 64;
  int c0 = cy * 64;
  const float* __restrict__ src = (c0 < 256) ? W : SW;
  int cc = (c0 < 256) ? c0 : c0 - 256;
  int r = t >> 2, q4 = (t & 3) * 16;
#pragma unroll
  for (int q = 0; q < 4; q++) {
    float4 v = *reinterpret_cast<const float4*>(src + (size_t)(k0 + r) * 256 + cc + q4 + q * 4);
    tile[q4 + q * 4 + 0][r] = f2bf(v.x);
    tile[q4 + q * 4 + 1][r] = f2bf(v.y);
    tile[q4 + q * 4 + 2][r] = f2bf(v.z);
    tile[q4 + q * 4 + 3][r] = f2bf(v.w);
  }
  __syncthreads();
  int c = t >> 2, kq = (t & 3) * 16;
#pragma unroll
  for (int q = 0; q < 2; q++) {
    bf16x8 v = *reinterpret_cast<const bf16x8*>(&tile[c][kq + q * 8]);
    *reinterpret_cast<bf16x8*>(Bt + (size_t)(c0 + c) * K + k0 + kq + q * 8) = v;
  }
}

__global__ __launch_bounds__(256) void prep_kernel(
    const float* __restrict__ x, unsigned short* __restrict__ xb, int total4, int t4b,
    const float* __restrict__ W0, const float* __restrict__ SW0, unsigned short* __restrict__ Bt0,
    const float* __restrict__ W1, const float* __restrict__ SW1, unsigned short* __restrict__ Bt1,
    const float* __restrict__ W2, const float* __restrict__ SW2, unsigned short* __restrict__ Bt2,
    unsigned short* __restrict__ hb_dummy, float* __restrict__ s_dummy) {
  __shared__ unsigned short tile[64][72];
  int b = blockIdx.x;
  int t = threadIdx.x;
  if (b < t4b) {
    if (b == 0) {  // dummy-row init (512B hb row + 4 floats of s)
      if (t < 64) reinterpret_cast<ushort4*>(hb_dummy)[t] = (ushort4){0, 0, 0, 0};
      if (t < 4) s_dummy[t] = -1e30f;
    }
    int i = b * 256 + t;
    if (i >= total4) return;
    float4 v = reinterpret_cast<const float4*>(x)[i];
    ushort4 o;
    o.x = f2bf(v.x); o.y = f2bf(v.y); o.z = f2bf(v.z); o.w = f2bf(v.w);
    reinterpret_cast<ushort4*>(xb)[i] = o;
  } else if (b < t4b + 16) {
    int local = b - t4b;
    transpose_body(W0, SW0, Bt0, 128, local & 1, local >> 1, tile, t);
  } else if (b < t4b + 48) {
    int local = b - t4b - 16;
    transpose_body(W1, SW1, Bt1, 256, local & 3, local >> 2, tile, t);
  } else {
    int local = b - t4b - 48;
    transpose_body(W2, SW2, Bt2, 256, local & 3, local >> 2, tile, t);
  }
}

// ---------------------------------------------------------------------------
// bf16 MFMA GEMM v8 (high-occupancy, no atomics):
// out[M][512] = x[M][K] @ [W|SW][K][512]
// Block = 128 rows x 64 cols, 4 waves of 32x64. Bs = 64 x K (32KB @K=256)
// -> 4 blocks/CU (launch_bounds(256,4)) = 16 waves/CU — 2x the residency of
// the R9 128-col structure, now WITHOUT the atomicMax that poisoned R7's
// test of this geometry. One barrier; A global->VGPR with 1-step reg dbuf.
// Grid 8*8*ceil(npanels/8); bid%8 == rg%8 -> all 8 col-groups of a row
// panel on one XCD (A L2-reuse, FETCH-proven).
//   cg 0..3 -> h (head=cg) + fused s/d epilogue; cg 4..7 -> skip (+Sb)
// ---------------------------------------------------------------------------
template <int K>
__global__ __launch_bounds__(256, 4) void gemm_mfma(
    const unsigned short* __restrict__ xb, const unsigned short* __restrict__ Bt,
    const float* __restrict__ Sb, const float* __restrict__ a_src,
    const float* __restrict__ a_dst, unsigned short* __restrict__ h,
    unsigned short* __restrict__ skipb, float* __restrict__ s,
    float* __restrict__ d, int M, int npanels) {
  __shared__ unsigned short Bs[64 * K];  // 16/32 KB

  const int t = threadIdx.x;
  const int xcdslot = blockIdx.x & 7;
  const int cg = (blockIdx.x >> 3) & 7;
  const int rg = (blockIdx.x >> 6) * 8 + xcdslot;
  if (rg >= npanels) return;
  const int rowBase = rg * 128;
  const int colB = cg * 64;  // column group in [0,512)

  const int w = t >> 6, lane = t & 63;
  const int wrow = w * 32;
  const int lrow = lane & 15, lq = lane >> 4;
  constexpr int nt = K >> 5;

  // ---- B fill: LDS linear dest, inverse-swizzled global source (rule 21).
  {
    constexpr int ROWCH = K >> 3;        // 16B chunks per row
    constexpr int ITERS = (64 * ROWCH) >> 8;
#pragma unroll
    for (int it = 0; it < ITERS; ++it) {
      int c = t + (it << 8);
      int lc = c / ROWCH;
      int ci = c & (ROWCH - 1);
      unsigned int src_off = ((unsigned int)(ci << 4)) ^ (unsigned int)((lc & 7) << 4);
      gload_lds16(Bt + (size_t)(colB + lc) * K + (src_off >> 1), Bs + (size_t)c * 8);
    }
  }

  // A fragment pointers (2 x 16 rows).
  const unsigned short* ap[2];
#pragma unroll
  for (int i = 0; i < 2; i++) {
    int gr = rowBase + wrow + i * 16 + lrow;
    if (gr >= M) gr = M - 1;
    ap[i] = xb + (size_t)gr * K + lq * 8;
  }

  // B read offsets: col = j*16+lrow, byte = col*K*2 + ((st*64+lq*16) ^ swz).
  const unsigned int bSwz = (unsigned int)((lrow & 7) << 4);  // j*16 ≡ 0 (mod 8)
  unsigned int bRow[4];
#pragma unroll
  for (int j = 0; j < 4; j++) bRow[j] = (unsigned int)((j * 16 + lrow) * (K * 2));

  f32x4 acc[2][4];
#pragma unroll
  for (int i = 0; i < 2; i++)
#pragma unroll
    for (int j = 0; j < 4; j++) acc[i][j] = (f32x4){0.f, 0.f, 0.f, 0.f};

  bf16x8 af[2][2];
#pragma unroll
  for (int i = 0; i < 2; i++) af[0][i] = *reinterpret_cast<const bf16x8*>(ap[i]);

  __syncthreads();  // B ready; only barrier in the kernel

#pragma unroll
  for (int st = 0; st < nt; ++st) {
    const int cur = st & 1, nxt = cur ^ 1;
    if (st + 1 < nt) {
#pragma unroll
      for (int i = 0; i < 2; i++)
        af[nxt][i] = *reinterpret_cast<const bf16x8*>(ap[i] + (st + 1) * 32);
    }
    bf16x8 bfr[4];
    const unsigned int kb = ((unsigned int)(st * 64) + (unsigned int)(lq << 4)) ^ bSwz;
#pragma unroll
    for (int j = 0; j < 4; j++)
      bfr[j] = *reinterpret_cast<const bf16x8*>((const char*)Bs + bRow[j] + kb);
#pragma unroll
    for (int i = 0; i < 2; i++)
#pragma unroll
      for (int j = 0; j < 4; j++)
        acc[i][j] = __builtin_amdgcn_mfma_f32_16x16x32_bf16(af[cur][i], bfr[j], acc[i][j], 0, 0, 0);
  }

  // ---- Epilogue. C/D layout: col=lane&15, row=(lane>>4)*4+reg
  if (cg < 4) {
#pragma unroll
    for (int i = 0; i < 2; i++) {
#pragma unroll
      for (int j = 0; j < 4; j++) {
        int gcol = colB + j * 16 + lrow;
#pragma unroll
        for (int r2 = 0; r2 < 4; r2++) {
          int grow = rowBase + wrow + i * 16 + lq * 4 + r2;
          if (grow < M) h[(size_t)grow * 256 + gcol] = f2bf(acc[i][j][r2]);
        }
      }
    }
    // fused s/d (this wave covers the FULL head; no max, no atomic)
    const int head = cg;
    float as_w[4], ad_w[4];
#pragma unroll
    for (int j = 0; j < 4; j++) {
      as_w[j] = a_src[head * 64 + j * 16 + lrow];
      ad_w[j] = a_dst[head * 64 + j * 16 + lrow];
    }
#pragma unroll
    for (int i = 0; i < 2; i++) {
#pragma unroll
      for (int r2 = 0; r2 < 4; r2++) {
        float ps = acc[i][0][r2] * as_w[0] + acc[i][1][r2] * as_w[1] +
                   acc[i][2][r2] * as_w[2] + acc[i][3][r2] * as_w[3];
        float pd = acc[i][0][r2] * ad_w[0] + acc[i][1][r2] * ad_w[1] +
                   acc[i][2][r2] * ad_w[2] + acc[i][3][r2] * ad_w[3];
#pragma unroll
        for (int off = 1; off < 16; off <<= 1) {  // reduce across lrow (same lq)
          ps += __shfl_xor(ps, off, 64);
          pd += __shfl_xor(pd, off, 64);
        }
        int grow = rowBase + wrow + i * 16 + lq * 4 + r2;
        if (grow < M && lrow == 0) { s[grow * 4 + head] = ps; d[grow * 4 + head] = pd; }
      }
    }
  } else {
#pragma unroll
    for (int i = 0; i < 2; i++) {
#pragma unroll
      for (int j = 0; j < 4; j++) {
        int c = colB - 256 + j * 16 + lrow;
        float sbv = Sb[c];
#pragma unroll
        for (int r2 = 0; r2 < 4; r2++) {
          int grow = rowBase + wrow + i * 16 + lq * 4 + r2;
          if (grow < M) skipb[(size_t)grow * 256 + c] = f2bf(acc[i][j][r2] + sbv);
        }
      }
    }
  }
}

// ---------------------------------------------------------------------------
// CSR build. Padding (multiple of 8) holds the DUMMY index Nn (written by
// offsets_kernel, no pad dispatch); s[Nn]=-1e30 -> ev==0, hb[Nn]=0.
// ---------------------------------------------------------------------------
__global__ void hist_kernel(const int* __restrict__ ei, int* __restrict__ counts, int E) {
  int e = blockIdx.x * 256 + threadIdx.x;
  if (e < E) atomicAdd(&counts[ei[E + e]], 1);
}

__global__ __launch_bounds__(256) void offsets_kernel(
    const int* __restrict__ counts, int* __restrict__ offsets,
    int* __restrict__ cursor, int* __restrict__ total,
    int* __restrict__ csr, int Nn) {
  int n = blockIdx.x * 256 + threadIdx.x;
  int lane = threadIdx.x & 63;
  int c = (n < Nn) ? counts[n] : 0;
  int pc = (c + 7) & ~7;
  int incl = pc;
#pragma unroll
  for (int off = 1; off < 64; off <<= 1) {
    int tv = __shfl_up(incl, off, 64);
    if (lane >= off) incl += tv;
  }
  int wavesum = __shfl(incl, 63, 64);
  int base = 0;
  if (lane == 63) base = atomicAdd(total, wavesum);
  base = __shfl(base, 63, 64);
  if (n < Nn) {
    int pos = base + incl - pc;
    offsets[n] = pos;
    cursor[n] = pos;
    for (int q = pos + c; q < pos + pc; ++q) csr[q] = Nn;  // dummy padding
  }
}

__global__ void scatter_kernel(const int* __restrict__ ei, int* __restrict__ cursor,
                               int* __restrict__ csr, int E) {
  int e = blockIdx.x * 256 + threadIdx.x;
  if (e < E) {
    int dn = ei[E + e];
    int pos = atomicAdd(&cursor[dn], 1);
    csr[pos] = ei[e];
  }
}

// ---------------------------------------------------------------------------
// Aggregation v4 (R10 verbatim — measured 76.2us): one wave per node, 8 edges
// per iteration. P1: lanes compute one (edge,head) ev each -> wave LDS.
// P2: halves process 4 edges each with b128 gathers + pkfma. Maskless via
// dummy node Nn. Softmax shift m = self-loop logit.
// ---------------------------------------------------------------------------
__global__ __launch_bounds__(256) void agg_kernel(
    const unsigned short* __restrict__ hb, const float* __restrict__ s,
    const float* __restrict__ d,
    const int* __restrict__ offsets, const int* __restrict__ counts,
    const int* __restrict__ csr,
    const float* __restrict__ b, const unsigned short* __restrict__ skipb,
    float* __restrict__ xout_f, unsigned short* __restrict__ xout_b,
    int Nn, int write_f) {
  __shared__ float evs_all[4][32];
  int wid = threadIdx.x >> 6;
  int n = blockIdx.x * 4 + wid;
  if (n >= Nn) return;
  int lane = threadIdx.x & 63;
  int sub = lane >> 5;
  int li = lane & 31;
  int head = li >> 3;   // == (lane>>3)&3 for all 64 lanes
  int col = li * 8;
  float* evs = evs_all[wid];

  int beg = offsets[n];
  int cnt = counts[n];
  int pend = beg + ((cnt + 7) & ~7);

  float dv = d[n * 4 + head];
  float sv = s[n * 4 + head];
  float m = leaky02(sv + dv);  // self-loop logit as the softmax shift

  f32x2 a2[4];
#pragma unroll
  for (int k2 = 0; k2 < 4; k2++) a2[k2] = (f32x2){0.f, 0.f};
  float dsum = 0.f;

  const int e8 = lane & 7;
  for (int i0 = beg; i0 < pend; i0 += 8) {
    // --- P1: one ev per lane (edge e8, this head) ---
    int snp = csr[i0 + e8];
    float lv = s[snp * 4 + head] + dv;
    float ev = __expf(leaky02(lv) - m);
    if (sub == 0) evs[li] = ev;  // li == head*8 + e8

    // --- P2: halves process 4 edges each ---
    int4 sn = *reinterpret_cast<const int4*>(csr + i0 + sub * 4);
    int eb = head * 8 + sub * 4;
    float ev0 = evs[eb + 0], ev1 = evs[eb + 1], ev2 = evs[eb + 2], ev3 = evs[eb + 3];
    dsum += ev0 + ev1 + ev2 + ev3;
    u32x4 w0 = __builtin_bit_cast(u32x4, *reinterpret_cast<const bf16x8*>(hb + (size_t)sn.x * HC + col));
    u32x4 w1 = __builtin_bit_cast(u32x4, *reinterpret_cast<const bf16x8*>(hb + (size_t)sn.y * HC + col));
    u32x4 w2 = __builtin_bit_cast(u32x4, *reinterpret_cast<const bf16x8*>(hb + (size_t)sn.z * HC + col));
    u32x4 w3 = __builtin_bit_cast(u32x4, *reinterpret_cast<const bf16x8*>(hb + (size_t)sn.w * HC + col));
    f32x2 e0 = (f32x2){ev0, ev0}, e1 = (f32x2){ev1, ev1};
    f32x2 e2 = (f32x2){ev2, ev2}, e3 = (f32x2){ev3, ev3};
#pragma unroll
    for (int k2 = 0; k2 < 4; k2++) {
      pkfma(a2[k2], e0, bfpair(w0[k2]));
      pkfma(a2[k2], e1, bfpair(w1[k2]));
      pkfma(a2[k2], e2, bfpair(w2[k2]));
      pkfma(a2[k2], e3, bfpair(w3[k2]));
    }
  }

#pragma unroll
  for (int k2 = 0; k2 < 4; k2++) {
    a2[k2].x += __shfl_xor(a2[k2].x, 32, 64);
    a2[k2].y += __shfl_xor(a2[k2].y, 32, 64);
  }
  dsum += __shfl_xor(dsum, 32, 64);

  // self loop: exp(m - m) == 1
  bf16x8 hs = *reinterpret_cast<const bf16x8*>(hb + (size_t)n * HC + col);
  float a[8];
#pragma unroll
  for (int k2 = 0; k2 < 4; k2++) { a[2 * k2] = a2[k2].x; a[2 * k2 + 1] = a2[k2].y; }
#pragma unroll
  for (int k = 0; k < 8; k++) a[k] += bf2f((unsigned short)hs[k]);
  dsum += 1.f;

  if (sub == 0) {
    float inv = 1.f / (dsum + 1e-16f);
    bf16x8 sk = *reinterpret_cast<const bf16x8*>(skipb + (size_t)n * HC + col);
    float4 b0 = *reinterpret_cast<const float4*>(b + col);
    float4 b1 = *reinterpret_cast<const float4*>(b + col + 4);
    float bv[8] = {b0.x, b0.y, b0.z, b0.w, b1.x, b1.y, b1.z, b1.w};
    float res[8];
#pragma unroll
    for (int k = 0; k < 8; k++) {
      float v = a[k] * inv + bv[k] + bf2f((unsigned short)sk[k]);
      res[k] = v > 0.f ? v : expm1f(v);
    }
    if (write_f) {
      float4 r0 = make_float4(res[0], res[1], res[2], res[3]);
      float4 r1 = make_float4(res[4], res[5], res[6], res[7]);
      *reinterpret_cast<float4*>(xout_f + (size_t)n * HC + col) = r0;
      *reinterpret_cast<float4*>(xout_f + (size_t)n * HC + col + 4) = r1;
    } else {
      bf16x8 o;
#pragma unroll
      for (int k = 0; k < 8; k++) o[k] = (short)f2bf(res[k]);
      *reinterpret_cast<bf16x8*>(xout_b + (size_t)n * HC + col) = o;
    }
  }
}

// ---------------------------------------------------------------------------
extern "C" void kernel_launch(void* const* d_in, const int* in_sizes, int n_in,
                              void* d_out, int out_size, void* d_ws, size_t ws_size,
                              hipStream_t stream) {
  const float* x = (const float*)d_in[0];
  const int* ei = (const int*)d_in[1];
  const int Nn = in_sizes[0] / 128;  // 50000
  const int E = in_sizes[1] / 2;     // 800000
  const int EPS = E + 7 * Nn;        // max padded CSR size (pad-8)

  const float* W[3]; const float* asrc[3]; const float* adst[3];
  const float* bb[3]; const float* SW[3]; const float* Sb[3];
  for (int l = 0; l < 3; l++) {
    W[l]    = (const float*)d_in[2 + 6 * l + 0];
    asrc[l] = (const float*)d_in[2 + 6 * l + 1];
    adst[l] = (const float*)d_in[2 + 6 * l + 2];
    bb[l]   = (const float*)d_in[2 + 6 * l + 3];
    SW[l]   = (const float*)d_in[2 + 6 * l + 4];
    Sb[l]   = (const float*)d_in[2 + 6 * l + 5];
  }

  // Workspace layout. hb gets +1 dummy row (index Nn); sbuf +4 dummy floats.
  char* p = (char*)d_ws;
  unsigned short* hb    = (unsigned short*)p; p += (size_t)(Nn + 1) * HC * 2;
  unsigned short* xb    = (unsigned short*)p; p += (size_t)Nn * HC * 2;
  unsigned short* x1b   = (unsigned short*)p; p += (size_t)Nn * 128 * 2;
  unsigned short* Bt0   = (unsigned short*)p; p += (size_t)512 * 128 * 2;
  unsigned short* Bt1   = (unsigned short*)p; p += (size_t)512 * 256 * 2;
  unsigned short* Bt2   = (unsigned short*)p; p += (size_t)512 * 256 * 2;
  unsigned short* skipb = (unsigned short*)p; p += (size_t)Nn * HC * 2;
  float* sbuf  = (float*)p; p += (size_t)Nn * HEADS * 4 + 16;
  float* dbuf  = (float*)p; p += (size_t)Nn * HEADS * 4;
  char* zero_base = p;
  int* counts  = (int*)p; p += (size_t)Nn * 4;
  int* total   = (int*)p; p += 16;
  size_t zero_bytes = (size_t)((char*)p - zero_base);
  int* offsets = (int*)p; p += ((size_t)Nn * 4 + 15) & ~(size_t)15;
  int* cursor  = (int*)p; p += ((size_t)Nn * 4 + 15) & ~(size_t)15;
  int* csr     = (int*)p; p += (size_t)EPS * 4;

  // --- Tiny memset: counts + total only (csr padding written by offsets) ---
  hipMemsetAsync(zero_base, 0, zero_bytes, stream);

  // --- Fused prep: convert x + 3 weight transposes + dummy-row init ---
  int t4 = Nn * 128 / 4;
  int t4b = (t4 + 255) / 256;
  prep_kernel<<<t4b + 80, 256, 0, stream>>>(x, x1b, t4, t4b,
                                            W[0], SW[0], Bt0,
                                            W[1], SW[1], Bt1,
                                            W[2], SW[2], Bt2,
                                            hb + (size_t)Nn * HC, sbuf + (size_t)Nn * 4);

  // --- CSR build (once; dst is layer-invariant) ---
  hist_kernel<<<(E + 255) / 256, 256, 0, stream>>>(ei, counts, E);
  offsets_kernel<<<(Nn + 255) / 256, 256, 0, stream>>>(counts, offsets, cursor, total, csr, Nn);
  scatter_kernel<<<(E + 255) / 256, 256, 0, stream>>>(ei, cursor, csr, E);

  // --- Layers ---
  const unsigned short* BtL[3] = {Bt0, Bt1, Bt2};
  int npanels = (Nn + 127) / 128;              // 391
  int nblocks = 8 * 8 * ((npanels + 7) / 8);   // 3136 (bid%8 == rg%8)
  int nblk4 = (Nn + 3) / 4;
  for (int l = 0; l < 3; l++) {
    const unsigned short* xin = (l == 0) ? x1b : xb;
    if (l == 0) {
      gemm_mfma<128><<<nblocks, 256, 0, stream>>>(
          xin, BtL[l], Sb[l], asrc[l], adst[l], hb, skipb, sbuf, dbuf, Nn, npanels);
    } else {
      gemm_mfma<256><<<nblocks, 256, 0, stream>>>(
          xin, BtL[l], Sb[l], asrc[l], adst[l], hb, skipb, sbuf, dbuf, Nn, npanels);
    }
    agg_kernel<<<nblk4, 256, 0, stream>>>(hb, sbuf, dbuf, offsets, counts, csr,
                                          bb[l], skipb, (float*)d_out, xb,
                                          Nn, (l == 2) ? 1 : 0);
  }
}